// Round 2
// baseline (335.544 us; speedup 1.0000x reference)
//
#include <hip/hip_runtime.h>

// BinaryLinear: out = (x @ sign(w)^T) * alpha[o],  alpha = mean(|w|, axis=1)
// x: [65536,1024] f32, w: [1024,1024] f32, out: [65536,1024] f32

typedef _Float16 half8 __attribute__((ext_vector_type(8)));
typedef _Float16 half4v __attribute__((ext_vector_type(4)));
typedef float f32x4 __attribute__((ext_vector_type(4)));

#define TOKENS 65536
#define INF 1024
#define OUTF 1024
#define BM 128
#define BN 128
#define BK 64
#define NT (INF / BK) /* 16 */

__device__ __forceinline__ void gload_lds16(const void* g, void* l) {
  __builtin_amdgcn_global_load_lds(
      (const __attribute__((address_space(1))) unsigned int*)g,
      (__attribute__((address_space(3))) unsigned int*)l, 16, 0, 0);
}

// ---------------- prep: alpha + sign(fp16) ----------------
__global__ __launch_bounds__(256) void bl_prep(const float* __restrict__ w,
                                               _Float16* __restrict__ sbin,
                                               float* __restrict__ alpha) {
  const int o = blockIdx.x;
  const int tid = threadIdx.x;
  const float4 v = ((const float4*)(w + (size_t)o * INF))[tid];
  float s = fabsf(v.x) + fabsf(v.y) + fabsf(v.z) + fabsf(v.w);
  half4v h;
  h[0] = (_Float16)((v.x > 0.f) ? 1.f : ((v.x < 0.f) ? -1.f : 0.f));
  h[1] = (_Float16)((v.y > 0.f) ? 1.f : ((v.y < 0.f) ? -1.f : 0.f));
  h[2] = (_Float16)((v.z > 0.f) ? 1.f : ((v.z < 0.f) ? -1.f : 0.f));
  h[3] = (_Float16)((v.w > 0.f) ? 1.f : ((v.w < 0.f) ? -1.f : 0.f));
  *(half4v*)(sbin + (size_t)o * INF + tid * 4) = h;
#pragma unroll
  for (int off = 32; off > 0; off >>= 1) s += __shfl_down(s, off, 64);
  __shared__ float red[4];
  const int wave = tid >> 6, lane = tid & 63;
  if (lane == 0) red[wave] = s;
  __syncthreads();
  if (tid == 0) alpha[o] = (red[0] + red[1] + red[2] + red[3]) * (1.0f / 1024.0f);
}

// ---------------- GEMM: 128x128 tile, BK=64, fp16 MFMA ----------------
__global__ __launch_bounds__(256, 2) void bl_gemm(const float* __restrict__ x,
                                                  const _Float16* __restrict__ sbin,
                                                  const float* __restrict__ alpha,
                                                  float* __restrict__ out) {
  __shared__ _Float16 ldsA[2][BM * BK];
  __shared__ _Float16 ldsB[2][BN * BK];

  const int tid = threadIdx.x;
  const int wave = tid >> 6;
  const int lane = tid & 63;
  const int wr = wave >> 1; // 0..1
  const int wc = wave & 1;  // 0..1

  // bijective XCD swizzle: group the 8 col-tiles of a row-panel on one XCD
  const int nwg = gridDim.x;           // 4096, divisible by 8
  const int chunk = nwg >> 3;
  const int wgid = (blockIdx.x & 7) * chunk + (blockIdx.x >> 3);
  const int rp = wgid >> 3; // row panel 0..511
  const int ct = wgid & 7;  // col tile 0..7
  const int bm0 = rp * BM;
  const int bn0 = ct * BN;

  // A staging: 1024 chunks of 8 floats; 4 chunks/thread
  size_t asrc[4];
  int adst[4];
#pragma unroll
  for (int it = 0; it < 4; ++it) {
    const int ci = it * 256 + tid;
    const int row = ci >> 3;
    const int c = ci & 7;
    asrc[it] = (size_t)(bm0 + row) * INF + c * 8;
    adst[it] = row * (BK * 2) + ((c ^ (row & 7)) << 4); // byte offset, XOR-swizzled
  }
  // B staging: global_load_lds, linear LDS dest; source address pre-swizzled
  size_t bsrc[4];
  int bldsbase[4];
#pragma unroll
  for (int it = 0; it < 4; ++it) {
    const int ci = it * 256 + wave * 64 + lane;
    const int row = ci >> 3;
    const int c = (ci & 7) ^ (row & 7);
    bsrc[it] = (size_t)(bn0 + row) * INF + c * 8;
    bldsbase[it] = (it * 256 + wave * 64) * 16; // wave-uniform byte base
  }

  f32x4 acc[4][4] = {};

  // ---- prologue: stage tile 0 into buffer 0 ----
#pragma unroll
  for (int it = 0; it < 4; ++it)
    gload_lds16(sbin + bsrc[it], (char*)&ldsB[0][0] + bldsbase[it]);
#pragma unroll
  for (int it = 0; it < 4; ++it) {
    const float4 v0 = *(const float4*)(x + asrc[it]);
    const float4 v1 = *(const float4*)(x + asrc[it] + 4);
    half8 h;
    h[0] = (_Float16)v0.x; h[1] = (_Float16)v0.y;
    h[2] = (_Float16)v0.z; h[3] = (_Float16)v0.w;
    h[4] = (_Float16)v1.x; h[5] = (_Float16)v1.y;
    h[6] = (_Float16)v1.z; h[7] = (_Float16)v1.w;
    *(half8*)((char*)&ldsA[0][0] + adst[it]) = h;
  }
  __syncthreads();

  int cur = 0;
  for (int kt = 0; kt < NT; ++kt) {
    const int nxt = cur ^ 1;
    const bool pf = (kt + 1 < NT);
    float4 av0[4], av1[4];
    if (pf) {
      const size_t koff = (size_t)(kt + 1) * BK;
#pragma unroll
      for (int it = 0; it < 4; ++it)
        gload_lds16(sbin + bsrc[it] + koff, (char*)&ldsB[nxt][0] + bldsbase[it]);
#pragma unroll
      for (int it = 0; it < 4; ++it) {
        av0[it] = *(const float4*)(x + asrc[it] + koff);
        av1[it] = *(const float4*)(x + asrc[it] + koff + 4);
      }
    }

    // ---- compute on current buffers ----
    const char* pA = (const char*)&ldsA[cur][0];
    const char* pB = (const char*)&ldsB[cur][0];
#pragma unroll
    for (int kk = 0; kk < 2; ++kk) {
      half8 af[4], bf[4];
      const int ck = kk * 4 + (lane >> 4);
#pragma unroll
      for (int m = 0; m < 4; ++m) {
        const int row = wr * 64 + m * 16 + (lane & 15);
        af[m] = *(const half8*)(pA + row * (BK * 2) + ((ck ^ (row & 7)) << 4));
      }
#pragma unroll
      for (int n = 0; n < 4; ++n) {
        const int row = wc * 64 + n * 16 + (lane & 15);
        bf[n] = *(const half8*)(pB + row * (BK * 2) + ((ck ^ (row & 7)) << 4));
      }
#pragma unroll
      for (int m = 0; m < 4; ++m)
#pragma unroll
        for (int n = 0; n < 4; ++n)
          acc[m][n] = __builtin_amdgcn_mfma_f32_16x16x32_f16(af[m], bf[n], acc[m][n], 0, 0, 0);
    }

    // ---- finish staging next tile (convert A in regs -> LDS) ----
    if (pf) {
#pragma unroll
      for (int it = 0; it < 4; ++it) {
        half8 h;
        h[0] = (_Float16)av0[it].x; h[1] = (_Float16)av0[it].y;
        h[2] = (_Float16)av0[it].z; h[3] = (_Float16)av0[it].w;
        h[4] = (_Float16)av1[it].x; h[5] = (_Float16)av1[it].y;
        h[6] = (_Float16)av1[it].z; h[7] = (_Float16)av1[it].w;
        *(half8*)((char*)&ldsA[nxt][0] + adst[it]) = h;
      }
    }
    __syncthreads();
    cur = nxt;
  }

  // ---- epilogue: scale by alpha[col], store f32 ----
#pragma unroll
  for (int n = 0; n < 4; ++n) {
    const int col = bn0 + wc * 64 + n * 16 + (lane & 15);
    const float al = alpha[col];
#pragma unroll
    for (int m = 0; m < 4; ++m) {
      const int row0 = bm0 + wr * 64 + m * 16 + ((lane >> 4) << 2);
#pragma unroll
      for (int j = 0; j < 4; ++j)
        out[(size_t)(row0 + j) * OUTF + col] = acc[m][n][j] * al;
    }
  }
}

extern "C" void kernel_launch(void* const* d_in, const int* in_sizes, int n_in,
                              void* d_out, int out_size, void* d_ws, size_t ws_size,
                              hipStream_t stream) {
  const float* x = (const float*)d_in[0];
  const float* w = (const float*)d_in[1];
  float* out = (float*)d_out;
  _Float16* sbin = (_Float16*)d_ws;                                  // 2 MB
  float* alpha = (float*)((char*)d_ws + (size_t)OUTF * INF * 2);     // 4 KB

  bl_prep<<<dim3(OUTF), dim3(256), 0, stream>>>(w, sbin, alpha);
  bl_gemm<<<dim3((TOKENS / BM) * (OUTF / BN)), dim3(256), 0, stream>>>(x, sbin, alpha, out);
}

// Round 3
// 303.215 us; speedup vs baseline: 1.1066x; 1.1066x over previous
//
#include <hip/hip_runtime.h>

// BinaryLinear: out = (x @ sign(w)^T) * alpha[o],  alpha = mean(|w|, axis=1)
// x: [65536,1024] f32, w: [1024,1024] f32, out: [65536,1024] f32
//
// R3: single-buffered 32KB LDS (m97 2-barrier regime), 4 blocks/CU.
//     A: reg-staged f32->fp16 convert, loads issued at top of compute phase.
//     B: global_load_lds width-16, source pre-swizzled (rule 21).

typedef _Float16 half8 __attribute__((ext_vector_type(8)));
typedef _Float16 half4v __attribute__((ext_vector_type(4)));
typedef float f32x4 __attribute__((ext_vector_type(4)));

#define TOKENS 65536
#define INF 1024
#define OUTF 1024
#define BM 128
#define BN 128
#define BK 64
#define NT (INF / BK) /* 16 */

__device__ __forceinline__ void gload_lds16(const void* g, void* l) {
  __builtin_amdgcn_global_load_lds(
      (const __attribute__((address_space(1))) unsigned int*)g,
      (__attribute__((address_space(3))) unsigned int*)l, 16, 0, 0);
}

// ---------------- prep: alpha + sign(fp16) ----------------
__global__ __launch_bounds__(256) void bl_prep(const float* __restrict__ w,
                                               _Float16* __restrict__ sbin,
                                               float* __restrict__ alpha) {
  const int o = blockIdx.x;
  const int tid = threadIdx.x;
  const float4 v = ((const float4*)(w + (size_t)o * INF))[tid];
  float s = fabsf(v.x) + fabsf(v.y) + fabsf(v.z) + fabsf(v.w);
  half4v h;
  h[0] = (_Float16)((v.x > 0.f) ? 1.f : ((v.x < 0.f) ? -1.f : 0.f));
  h[1] = (_Float16)((v.y > 0.f) ? 1.f : ((v.y < 0.f) ? -1.f : 0.f));
  h[2] = (_Float16)((v.z > 0.f) ? 1.f : ((v.z < 0.f) ? -1.f : 0.f));
  h[3] = (_Float16)((v.w > 0.f) ? 1.f : ((v.w < 0.f) ? -1.f : 0.f));
  *(half4v*)(sbin + (size_t)o * INF + tid * 4) = h;
#pragma unroll
  for (int off = 32; off > 0; off >>= 1) s += __shfl_down(s, off, 64);
  __shared__ float red[4];
  const int wave = tid >> 6, lane = tid & 63;
  if (lane == 0) red[wave] = s;
  __syncthreads();
  if (tid == 0) alpha[o] = (red[0] + red[1] + red[2] + red[3]) * (1.0f / 1024.0f);
}

// ---------------- GEMM: 128x128 tile, BK=64, fp16 MFMA, single-buffered ----------------
__global__ __launch_bounds__(256, 4) void bl_gemm(const float* __restrict__ x,
                                                  const _Float16* __restrict__ sbin,
                                                  const float* __restrict__ alpha,
                                                  float* __restrict__ out) {
  __shared__ _Float16 ldsA[BM * BK];  // 16 KB
  __shared__ _Float16 ldsB[BN * BK];  // 16 KB

  const int tid = threadIdx.x;
  const int wave = tid >> 6;
  const int lane = tid & 63;
  const int wr = wave >> 1; // 0..1
  const int wc = wave & 1;  // 0..1

  // bijective XCD swizzle: group the 8 col-tiles of a row-panel on one XCD
  const int nwg = gridDim.x;           // 4096, divisible by 8
  const int chunk = nwg >> 3;
  const int wgid = (blockIdx.x & 7) * chunk + (blockIdx.x >> 3);
  const int rp = wgid >> 3; // row panel 0..511
  const int ct = wgid & 7;  // col tile 0..7
  const int bm0 = rp * BM;
  const int bn0 = ct * BN;

  // A staging: 1024 chunks of 8 floats; 4 chunks/thread; swizzle on LDS dest
  size_t asrc[4];
  int adst[4];
#pragma unroll
  for (int it = 0; it < 4; ++it) {
    const int ci = it * 256 + tid;
    const int row = ci >> 3;
    const int c = ci & 7;
    asrc[it] = (size_t)(bm0 + row) * INF + c * 8;
    adst[it] = row * (BK * 2) + ((c ^ (row & 7)) << 4); // byte offset, XOR-swizzled
  }
  // B staging: global_load_lds, linear LDS dest; source address pre-swizzled
  size_t bsrc[4];
  int bldsbase[4];
#pragma unroll
  for (int it = 0; it < 4; ++it) {
    const int ci = it * 256 + wave * 64 + lane;
    const int row = ci >> 3;
    const int c = (ci & 7) ^ (row & 7);
    bsrc[it] = (size_t)(bn0 + row) * INF + c * 8;
    bldsbase[it] = (it * 256 + wave * 64) * 16; // wave-uniform byte base
  }

  f32x4 acc[4][4] = {};

  // ---- prologue: stage tile 0 ----
#pragma unroll
  for (int it = 0; it < 4; ++it)
    gload_lds16(sbin + bsrc[it], (char*)&ldsB[0] + bldsbase[it]);
#pragma unroll
  for (int it = 0; it < 4; ++it) {
    const float4 v0 = *(const float4*)(x + asrc[it]);
    const float4 v1 = *(const float4*)(x + asrc[it] + 4);
    half8 h;
    h[0] = (_Float16)v0.x; h[1] = (_Float16)v0.y;
    h[2] = (_Float16)v0.z; h[3] = (_Float16)v0.w;
    h[4] = (_Float16)v1.x; h[5] = (_Float16)v1.y;
    h[6] = (_Float16)v1.z; h[7] = (_Float16)v1.w;
    *(half8*)((char*)&ldsA[0] + adst[it]) = h;
  }
  __syncthreads();

  for (int kt = 0; kt < NT; ++kt) {
    const bool pf = (kt + 1 < NT);
    float4 av0[4], av1[4];
    // issue next A-tile loads early: latency hides under this tile's MFMA phase
    if (pf) {
      const size_t koff = (size_t)(kt + 1) * BK;
#pragma unroll
      for (int it = 0; it < 4; ++it) {
        av0[it] = *(const float4*)(x + asrc[it] + koff);
        av1[it] = *(const float4*)(x + asrc[it] + koff + 4);
      }
    }

    // ---- compute on current tile ----
    const char* pA = (const char*)&ldsA[0];
    const char* pB = (const char*)&ldsB[0];
#pragma unroll
    for (int kk = 0; kk < 2; ++kk) {
      half8 af[4], bf[4];
      const int ck = kk * 4 + (lane >> 4);
#pragma unroll
      for (int m = 0; m < 4; ++m) {
        const int row = wr * 64 + m * 16 + (lane & 15);
        af[m] = *(const half8*)(pA + row * (BK * 2) + ((ck ^ (row & 7)) << 4));
      }
#pragma unroll
      for (int n = 0; n < 4; ++n) {
        const int row = wc * 64 + n * 16 + (lane & 15);
        bf[n] = *(const half8*)(pB + row * (BK * 2) + ((ck ^ (row & 7)) << 4));
      }
#pragma unroll
      for (int m = 0; m < 4; ++m)
#pragma unroll
        for (int n = 0; n < 4; ++n)
          acc[m][n] = __builtin_amdgcn_mfma_f32_16x16x32_f16(af[m], bf[n], acc[m][n], 0, 0, 0);
    }

    __syncthreads(); // all waves done reading tile kt

    if (pf) {
      const size_t koff = (size_t)(kt + 1) * BK;
#pragma unroll
      for (int it = 0; it < 4; ++it)
        gload_lds16(sbin + bsrc[it] + koff, (char*)&ldsB[0] + bldsbase[it]);
#pragma unroll
      for (int it = 0; it < 4; ++it) {
        half8 h;
        h[0] = (_Float16)av0[it].x; h[1] = (_Float16)av0[it].y;
        h[2] = (_Float16)av0[it].z; h[3] = (_Float16)av0[it].w;
        h[4] = (_Float16)av1[it].x; h[5] = (_Float16)av1[it].y;
        h[6] = (_Float16)av1[it].z; h[7] = (_Float16)av1[it].w;
        *(half8*)((char*)&ldsA[0] + adst[it]) = h;
      }
      __syncthreads(); // tile kt+1 staged (vmcnt+lgkm drained by barrier)
    }
  }

  // ---- epilogue: scale by alpha[col], store f32 ----
#pragma unroll
  for (int n = 0; n < 4; ++n) {
    const int col = bn0 + wc * 64 + n * 16 + (lane & 15);
    const float al = alpha[col];
#pragma unroll
    for (int m = 0; m < 4; ++m) {
      const int row0 = bm0 + wr * 64 + m * 16 + ((lane >> 4) << 2);
#pragma unroll
      for (int j = 0; j < 4; ++j)
        out[(size_t)(row0 + j) * OUTF + col] = acc[m][n][j] * al;
    }
  }
}

extern "C" void kernel_launch(void* const* d_in, const int* in_sizes, int n_in,
                              void* d_out, int out_size, void* d_ws, size_t ws_size,
                              hipStream_t stream) {
  const float* x = (const float*)d_in[0];
  const float* w = (const float*)d_in[1];
  float* out = (float*)d_out;
  _Float16* sbin = (_Float16*)d_ws;                                  // 2 MB
  float* alpha = (float*)((char*)d_ws + (size_t)OUTF * INF * 2);     // 4 KB

  bl_prep<<<dim3(OUTF), dim3(256), 0, stream>>>(w, sbin, alpha);
  bl_gemm<<<dim3((TOKENS / BM) * (OUTF / BN)), dim3(256), 0, stream>>>(x, sbin, alpha, out);
}

// Round 4
// 271.596 us; speedup vs baseline: 1.2355x; 1.1164x over previous
//
#include <hip/hip_runtime.h>

// BinaryLinear: out = (x @ sign(w)^T) * alpha[o],  alpha = mean(|w|, axis=1)
// x: [65536,1024] f32, w: [1024,1024] f32, out: [65536,1024] f32
//
// R4: 256x256 tile, BK=32, 4-buffer LDS rotation (128KB), 8 waves,
//     64 phases with counted vmcnt(6) gates (T3+T4), XOR-swizzled LDS (T2),
//     setprio around MFMA (T5), fused fp32->fp16 A conversion (T14-style
//     issue-early/write-late, 2-phase lead), raw s_barrier (no drain).

typedef _Float16 half8 __attribute__((ext_vector_type(8)));
typedef _Float16 half4v __attribute__((ext_vector_type(4)));
typedef float f32x4 __attribute__((ext_vector_type(4)));

#define TOKENS 65536
#define INF 1024
#define OUTF 1024
#define BM 256
#define BN 256
#define BK 32
#define NKT (INF / BK) /* 32 K-tiles */

__device__ __forceinline__ void gload_lds16(const void* g, void* l) {
  __builtin_amdgcn_global_load_lds(
      (const __attribute__((address_space(1))) unsigned int*)g,
      (__attribute__((address_space(3))) unsigned int*)l, 16, 0, 0);
}

__device__ __forceinline__ half8 cvt8(float4 a, float4 b) {
  half8 h;
  h[0] = (_Float16)a.x; h[1] = (_Float16)a.y;
  h[2] = (_Float16)a.z; h[3] = (_Float16)a.w;
  h[4] = (_Float16)b.x; h[5] = (_Float16)b.y;
  h[6] = (_Float16)b.z; h[7] = (_Float16)b.w;
  return h;
}

// ---------------- prep: alpha + sign(fp16) ----------------
__global__ __launch_bounds__(256) void bl_prep(const float* __restrict__ w,
                                               _Float16* __restrict__ sbin,
                                               float* __restrict__ alpha) {
  const int o = blockIdx.x;
  const int tid = threadIdx.x;
  const float4 v = ((const float4*)(w + (size_t)o * INF))[tid];
  float s = fabsf(v.x) + fabsf(v.y) + fabsf(v.z) + fabsf(v.w);
  half4v h;
  h[0] = (_Float16)((v.x > 0.f) ? 1.f : ((v.x < 0.f) ? -1.f : 0.f));
  h[1] = (_Float16)((v.y > 0.f) ? 1.f : ((v.y < 0.f) ? -1.f : 0.f));
  h[2] = (_Float16)((v.z > 0.f) ? 1.f : ((v.z < 0.f) ? -1.f : 0.f));
  h[3] = (_Float16)((v.w > 0.f) ? 1.f : ((v.w < 0.f) ? -1.f : 0.f));
  *(half4v*)(sbin + (size_t)o * INF + tid * 4) = h;
#pragma unroll
  for (int off = 32; off > 0; off >>= 1) s += __shfl_down(s, off, 64);
  __shared__ float red[4];
  const int wave = tid >> 6, lane = tid & 63;
  if (lane == 0) red[wave] = s;
  __syncthreads();
  if (tid == 0) alpha[o] = (red[0] + red[1] + red[2] + red[3]) * (1.0f / 1024.0f);
}

// ---------------- GEMM ----------------
__global__ __launch_bounds__(512, 2) void bl_gemm(const float* __restrict__ x,
                                                  const _Float16* __restrict__ sbin,
                                                  const float* __restrict__ alpha,
                                                  float* __restrict__ out) {
  __shared__ _Float16 ldsA[4][BM * BK]; // 4 x 16KB
  __shared__ _Float16 ldsB[4][BN * BK]; // 4 x 16KB

  const int tid = threadIdx.x;
  const int lane = tid & 63;
  const int wid = tid >> 6;
  const int l15 = lane & 15;
  const int kc = lane >> 4; // 0..3, selects 16B chunk (k-slice) of a row
  const int wr = wid >> 2;  // 0..1
  const int wc = wid & 3;   // 0..3

  // XCD chunked swizzle: 1024 blocks -> 128 consecutive per XCD
  const int bid = blockIdx.x;
  const int wgid = (bid & 7) * 128 + (bid >> 3);
  const int bm0 = (wgid >> 2) * BM; // row panel 0..255
  const int bn0 = (wgid & 3) * BN;  // col tile 0..3

  // staging geometry: per half-tile (128 rows x 32 k), thread t owns chunk t:
  //   row = t>>2, chunk-in-row = t&3 ; LDS slot = chunk ^ ((row>>1)&3)
  const int rw = tid >> 2;
  const int cA = tid & 3;
  const int swz = cA ^ ((tid >> 3) & 3);

  size_t aSrc[2], bSrc[2];
  int aWr[2], bDst[2];
#pragma unroll
  for (int h = 0; h < 2; ++h) {
    aSrc[h] = (size_t)(bm0 + h * 128 + rw) * INF + cA * 8;  // linear source
    bSrc[h] = (size_t)(bn0 + h * 128 + rw) * INF + swz * 8; // pre-swizzled source
    aWr[h] = h * 8192 + rw * 64 + swz * 16;                 // swizzled LDS dest (ds_write)
    bDst[h] = h * 8192 + tid * 16;                          // linear LDS dest (gload_lds)
  }
  // fragment-read addressing (both A and B tiles are [256 rows][32 k] fp16)
  const int slotR = (kc ^ ((l15 >> 1) & 3)) * 16;
  const int aRd = (wr * 128 + l15) * 64 + slotR; // + m*1024
  const int bRd = (wc * 64 + l15) * 64 + slotR;  // + n*1024

  f32x4 acc[8][4] = {};
  float4 stA[2][2]; // A-convert pipeline slots (slot = phase parity = half-tile)
  half8 bf0, bf1, bf2, bf3;

  // ---------------- prologue: K-tiles 0,1 ----------------
  {
    float4 p00 = *(const float4*)(x + aSrc[0]);
    float4 p01 = *(const float4*)(x + aSrc[0] + 4);
    float4 p10 = *(const float4*)(x + aSrc[1]);
    float4 p11 = *(const float4*)(x + aSrc[1] + 4);
    gload_lds16(sbin + bSrc[0], (char*)&ldsB[0][0] + bDst[0]);
    gload_lds16(sbin + bSrc[1], (char*)&ldsB[0][0] + bDst[1]);
    asm volatile("" ::: "memory"); // T0 group precedes T1 group in vmcnt order
    stA[0][0] = *(const float4*)(x + aSrc[0] + BK);
    stA[0][1] = *(const float4*)(x + aSrc[0] + BK + 4);
    stA[1][0] = *(const float4*)(x + aSrc[1] + BK);
    stA[1][1] = *(const float4*)(x + aSrc[1] + BK + 4);
    gload_lds16(sbin + bSrc[0] + BK, (char*)&ldsB[1][0] + bDst[0]);
    gload_lds16(sbin + bSrc[1] + BK, (char*)&ldsB[1][0] + bDst[1]);
    *(half8*)((char*)&ldsA[0][0] + aWr[0]) = cvt8(p00, p01);
    *(half8*)((char*)&ldsA[0][0] + aWr[1]) = cvt8(p10, p11);
    asm volatile("s_waitcnt vmcnt(6) lgkmcnt(0)" ::: "memory");
    __builtin_amdgcn_s_barrier();
    asm volatile("" ::: "memory");
  }

// Phase(T, h): cvt+write A of K-tile T+1 (loaded 2 phases ago); issue stage of
// K-tile T+2 (A->regs, B->gload_lds); gate once per K-tile (h==1); barrier;
// 16 MFMA on half h of K-tile T.
#define PHASE(Tk_, KM_, H_)                                                          \
  {                                                                                  \
    constexpr int bR_ = (KM_) & 3;                                                   \
    constexpr int bW_ = ((KM_) + 1) & 3;                                             \
    constexpr int bS_ = ((KM_) + 2) & 3;                                             \
    const int Tk__ = (Tk_);                                                          \
    if (Tk__ + 1 < NKT)                                                              \
      *(half8*)((char*)&ldsA[bW_][0] + aWr[H_]) = cvt8(stA[H_][0], stA[H_][1]);      \
    if (Tk__ + 2 < NKT) {                                                            \
      const float* gp_ = x + aSrc[H_] + (size_t)(Tk__ + 2) * BK;                     \
      stA[H_][0] = *(const float4*)gp_;                                              \
      stA[H_][1] = *(const float4*)(gp_ + 4);                                        \
      gload_lds16(sbin + bSrc[H_] + (size_t)(Tk__ + 2) * BK,                         \
                  (char*)&ldsB[bS_][0] + bDst[H_]);                                  \
    }                                                                                \
    if ((H_) == 1 && Tk__ + 1 < NKT) {                                               \
      if (Tk__ + 2 < NKT)                                                            \
        asm volatile("s_waitcnt vmcnt(6) lgkmcnt(0)" ::: "memory");                  \
      else                                                                           \
        asm volatile("s_waitcnt vmcnt(0) lgkmcnt(0)" ::: "memory");                  \
    }                                                                                \
    const char* pa_ = (const char*)&ldsA[bR_][0] + aRd + (H_)*4096;                  \
    half8 af0 = *(const half8*)(pa_);                                                \
    half8 af1 = *(const half8*)(pa_ + 1024);                                         \
    half8 af2 = *(const half8*)(pa_ + 2048);                                         \
    half8 af3 = *(const half8*)(pa_ + 3072);                                         \
    if ((H_) == 0) {                                                                 \
      const char* pb_ = (const char*)&ldsB[bR_][0] + bRd;                            \
      bf0 = *(const half8*)(pb_);                                                    \
      bf1 = *(const half8*)(pb_ + 1024);                                             \
      bf2 = *(const half8*)(pb_ + 2048);                                             \
      bf3 = *(const half8*)(pb_ + 3072);                                             \
    }                                                                                \
    asm volatile("" ::: "memory");                                                   \
    __builtin_amdgcn_s_barrier();                                                    \
    asm volatile("" ::: "memory");                                                   \
    __builtin_amdgcn_s_setprio(1);                                                   \
    acc[(H_)*4 + 0][0] = __builtin_amdgcn_mfma_f32_16x16x32_f16(af0, bf0, acc[(H_)*4 + 0][0], 0, 0, 0); \
    acc[(H_)*4 + 0][1] = __builtin_amdgcn_mfma_f32_16x16x32_f16(af0, bf1, acc[(H_)*4 + 0][1], 0, 0, 0); \
    acc[(H_)*4 + 0][2] = __builtin_amdgcn_mfma_f32_16x16x32_f16(af0, bf2, acc[(H_)*4 + 0][2], 0, 0, 0); \
    acc[(H_)*4 + 0][3] = __builtin_amdgcn_mfma_f32_16x16x32_f16(af0, bf3, acc[(H_)*4 + 0][3], 0, 0, 0); \
    acc[(H_)*4 + 1][0] = __builtin_amdgcn_mfma_f32_16x16x32_f16(af1, bf0, acc[(H_)*4 + 1][0], 0, 0, 0); \
    acc[(H_)*4 + 1][1] = __builtin_amdgcn_mfma_f32_16x16x32_f16(af1, bf1, acc[(H_)*4 + 1][1], 0, 0, 0); \
    acc[(H_)*4 + 1][2] = __builtin_amdgcn_mfma_f32_16x16x32_f16(af1, bf2, acc[(H_)*4 + 1][2], 0, 0, 0); \
    acc[(H_)*4 + 1][3] = __builtin_amdgcn_mfma_f32_16x16x32_f16(af1, bf3, acc[(H_)*4 + 1][3], 0, 0, 0); \
    acc[(H_)*4 + 2][0] = __builtin_amdgcn_mfma_f32_16x16x32_f16(af2, bf0, acc[(H_)*4 + 2][0], 0, 0, 0); \
    acc[(H_)*4 + 2][1] = __builtin_amdgcn_mfma_f32_16x16x32_f16(af2, bf1, acc[(H_)*4 + 2][1], 0, 0, 0); \
    acc[(H_)*4 + 2][2] = __builtin_amdgcn_mfma_f32_16x16x32_f16(af2, bf2, acc[(H_)*4 + 2][2], 0, 0, 0); \
    acc[(H_)*4 + 2][3] = __builtin_amdgcn_mfma_f32_16x16x32_f16(af2, bf3, acc[(H_)*4 + 2][3], 0, 0, 0); \
    acc[(H_)*4 + 3][0] = __builtin_amdgcn_mfma_f32_16x16x32_f16(af3, bf0, acc[(H_)*4 + 3][0], 0, 0, 0); \
    acc[(H_)*4 + 3][1] = __builtin_amdgcn_mfma_f32_16x16x32_f16(af3, bf1, acc[(H_)*4 + 3][1], 0, 0, 0); \
    acc[(H_)*4 + 3][2] = __builtin_amdgcn_mfma_f32_16x16x32_f16(af3, bf2, acc[(H_)*4 + 3][2], 0, 0, 0); \
    acc[(H_)*4 + 3][3] = __builtin_amdgcn_mfma_f32_16x16x32_f16(af3, bf3, acc[(H_)*4 + 3][3], 0, 0, 0); \
    __builtin_amdgcn_s_setprio(0);                                                   \
  }

#pragma unroll 1
  for (int tq = 0; tq < 8; ++tq) {
    const int Tb = tq * 4;
    PHASE(Tb + 0, 0, 0)
    PHASE(Tb + 0, 0, 1)
    PHASE(Tb + 1, 1, 0)
    PHASE(Tb + 1, 1, 1)
    PHASE(Tb + 2, 2, 0)
    PHASE(Tb + 2, 2, 1)
    PHASE(Tb + 3, 3, 0)
    PHASE(Tb + 3, 3, 1)
  }
#undef PHASE

  // ---------------- epilogue: scale by alpha[col], store f32 ----------------
  float al[4];
#pragma unroll
  for (int n = 0; n < 4; ++n) al[n] = alpha[bn0 + wc * 64 + n * 16 + l15];
#pragma unroll
  for (int m = 0; m < 8; ++m) {
    const int row0 = bm0 + wr * 128 + m * 16 + kc * 4;
#pragma unroll
    for (int n = 0; n < 4; ++n) {
      const int col = bn0 + wc * 64 + n * 16 + l15;
#pragma unroll
      for (int j = 0; j < 4; ++j)
        out[(size_t)(row0 + j) * OUTF + col] = acc[m][n][j] * al[n];
    }
  }
}

extern "C" void kernel_launch(void* const* d_in, const int* in_sizes, int n_in,
                              void* d_out, int out_size, void* d_ws, size_t ws_size,
                              hipStream_t stream) {
  const float* x = (const float*)d_in[0];
  const float* w = (const float*)d_in[1];
  float* out = (float*)d_out;
  _Float16* sbin = (_Float16*)d_ws;                              // 2 MB
  float* alpha = (float*)((char*)d_ws + (size_t)OUTF * INF * 2); // 4 KB

  bl_prep<<<dim3(OUTF), dim3(256), 0, stream>>>(w, sbin, alpha);
  bl_gemm<<<dim3((TOKENS / BM) * (OUTF / BN)), dim3(512), 0, stream>>>(x, sbin, alpha, out);
}

// Round 5
// 214.441 us; speedup vs baseline: 1.5647x; 1.2665x over previous
//
#include <hip/hip_runtime.h>

// BinaryLinear: out = (x @ sign(w)^T) * alpha[o],  alpha = mean(|w|, axis=1)
// x: [65536,1024] f32, w: [1024,1024] f32, out: [65536,1024] f32
//
// R5: 256x256 tile, BK=32, 4-buffer LDS rotation (128KB), 8 waves, 64 uniform
//     phases. A-staging via inline-asm global_load_dwordx4 (compiler-untracked;
//     manual counted vmcnt), 4-phase A-reg lead; B via global_load_lds, 2-tile
//     lead, gate vmcnt(6). Two barriers per phase (m201), setprio around MFMA.

typedef _Float16 half8 __attribute__((ext_vector_type(8)));
typedef _Float16 half4v __attribute__((ext_vector_type(4)));
typedef float f32x4 __attribute__((ext_vector_type(4)));

#define TOKENS 65536
#define INF 1024
#define OUTF 1024
#define BM 256
#define BN 256
#define BK 32
#define NKT 32

__device__ __forceinline__ void gload_lds16(const void* g, void* l) {
  __builtin_amdgcn_global_load_lds(
      (const __attribute__((address_space(1))) unsigned int*)g,
      (__attribute__((address_space(3))) unsigned int*)l, 16, 0, 0);
}

__device__ __forceinline__ half8 cvt8(f32x4 a, f32x4 b) {
  half8 h;
  h[0] = (_Float16)a[0]; h[1] = (_Float16)a[1];
  h[2] = (_Float16)a[2]; h[3] = (_Float16)a[3];
  h[4] = (_Float16)b[0]; h[5] = (_Float16)b[1];
  h[6] = (_Float16)b[2]; h[7] = (_Float16)b[3];
  return h;
}

// two 16B global loads, compiler-untracked (manual vmcnt accounting)
#define ALOAD(d0, d1, ap)                                                      \
  asm volatile("global_load_dwordx4 %0, %2, off\n\t"                           \
               "global_load_dwordx4 %1, %2, off offset:16"                     \
               : "=&v"(d0), "=&v"(d1)                                          \
               : "v"(ap)                                                       \
               : "memory")

// ---------------- prep: alpha + sign(fp16) ----------------
__global__ __launch_bounds__(256) void bl_prep(const float* __restrict__ w,
                                               _Float16* __restrict__ sbin,
                                               float* __restrict__ alpha) {
  const int o = blockIdx.x;
  const int tid = threadIdx.x;
  const float4 v = ((const float4*)(w + (size_t)o * INF))[tid];
  float s = fabsf(v.x) + fabsf(v.y) + fabsf(v.z) + fabsf(v.w);
  half4v h;
  h[0] = (_Float16)((v.x > 0.f) ? 1.f : ((v.x < 0.f) ? -1.f : 0.f));
  h[1] = (_Float16)((v.y > 0.f) ? 1.f : ((v.y < 0.f) ? -1.f : 0.f));
  h[2] = (_Float16)((v.z > 0.f) ? 1.f : ((v.z < 0.f) ? -1.f : 0.f));
  h[3] = (_Float16)((v.w > 0.f) ? 1.f : ((v.w < 0.f) ? -1.f : 0.f));
  *(half4v*)(sbin + (size_t)o * INF + tid * 4) = h;
#pragma unroll
  for (int off = 32; off > 0; off >>= 1) s += __shfl_down(s, off, 64);
  __shared__ float red[4];
  const int wave = tid >> 6, lane = tid & 63;
  if (lane == 0) red[wave] = s;
  __syncthreads();
  if (tid == 0) alpha[o] = (red[0] + red[1] + red[2] + red[3]) * (1.0f / 1024.0f);
}

// ---------------- GEMM ----------------
__global__ __launch_bounds__(512, 1) void bl_gemm(const float* __restrict__ x,
                                                  const _Float16* __restrict__ sbin,
                                                  const float* __restrict__ alpha,
                                                  float* __restrict__ out) {
  __shared__ _Float16 ldsA[4][BM * BK]; // 4 x 16KB
  __shared__ _Float16 ldsB[4][BN * BK]; // 4 x 16KB

  const int tid = threadIdx.x;
  const int lane = tid & 63;
  const int wid = tid >> 6;
  const int l15 = lane & 15;
  const int kc = lane >> 4; // 0..3
  const int wr = wid >> 2;  // 0..1
  const int wc = wid & 3;   // 0..3

  // XCD chunked swizzle: 1024 blocks -> 128 consecutive per XCD
  const int bid = blockIdx.x;
  const int wgid = (bid & 7) * 128 + (bid >> 3);
  const int bm0 = (wgid >> 2) * BM;
  const int bn0 = (wgid & 3) * BN;

  // staging: thread owns row rw = tid>>2 (of 128-row half), 8-elem chunk cA
  const int rw = tid >> 2;
  const int cA = tid & 3;
  const int swz = cA ^ ((rw >> 1) & 3);

  size_t aOff[2], bOff[2];
  int aWr[2], bDst[2];
#pragma unroll
  for (int h = 0; h < 2; ++h) {
    aOff[h] = (size_t)(bm0 + h * 128 + rw) * INF + cA * 8;  // float elems
    bOff[h] = (size_t)(bn0 + h * 128 + rw) * INF + swz * 8; // fp16 elems, pre-swizzled
    aWr[h] = (h * 128 + rw) * 64 + swz * 16;                // byte, swizzled ds_write
    bDst[h] = h * 8192 + tid * 16;                          // byte, linear gload dest
  }
  // fragment-read addressing: row*64B + swizzled 16B slot
  const int sl = (kc ^ ((l15 >> 1) & 3)) * 16;
  const int aRdB = (wr * 128 + l15) * 64 + sl; // + mf*1024
  const int bRdB = (wc * 64 + l15) * 64 + sl;  // + n*1024

  f32x4 acc[8][4] = {};
  f32x4 stA[2][2][2]; // [set p=T&1][half][2]; static indices only
  half8 bf0, bf1, bf2, bf3;

  // ---------------- prologue ----------------
  {
#pragma unroll
    for (int t = 0; t < 2; ++t)
#pragma unroll
      for (int h = 0; h < 2; ++h) {
        f32x4 v0 = *(const f32x4*)(x + aOff[h] + t * BK);
        f32x4 v1 = *(const f32x4*)(x + aOff[h] + t * BK + 4);
        *(half8*)((char*)&ldsA[t][0] + aWr[h]) = cvt8(v0, v1);
      }
#pragma unroll
    for (int t = 0; t < 2; ++t)
#pragma unroll
      for (int h = 0; h < 2; ++h)
        gload_lds16(sbin + bOff[h] + t * BK, (char*)&ldsB[t][0] + bDst[h]);
    ALOAD(stA[0][0][0], stA[0][0][1], x + aOff[0] + 2 * BK);
    ALOAD(stA[0][1][0], stA[0][1][1], x + aOff[1] + 2 * BK);
    ALOAD(stA[1][0][0], stA[1][0][1], x + aOff[0] + 3 * BK);
    ALOAD(stA[1][1][0], stA[1][1][1], x + aOff[1] + 3 * BK);
    asm volatile("s_waitcnt vmcnt(0) lgkmcnt(0)" ::: "memory");
    __builtin_amdgcn_s_barrier();
  }

// Phase (Tk, KM=Tk&3 literal, H): uniform, issues exactly [A,A,B] vmem.
//  vmcnt(10): A-regs (loaded 4 phases ago) ready.
//  gate h==1: vmcnt(6) -> B of tile Tk+1 in LDS; lgkmcnt(0) -> A writes drained.
#define PH(Tk_, KM_, H_)                                                       \
  {                                                                            \
    constexpr int bRd_ = (KM_) & 3;                                            \
    constexpr int bWr_ = ((KM_) + 2) & 3;                                      \
    constexpr int p_ = (KM_) & 1;                                              \
    const int tA_ = ((Tk_) + 4 < NKT) ? (Tk_) + 4 : NKT - 1;                   \
    const int tB_ = ((Tk_) + 2 < NKT) ? (Tk_) + 2 : NKT - 1;                   \
    asm volatile("s_waitcnt vmcnt(10)" ::: "memory");                          \
    __builtin_amdgcn_sched_barrier(0);                                         \
    *(half8*)((char*)&ldsA[bWr_][0] + aWr[H_]) =                               \
        cvt8(stA[p_][H_][0], stA[p_][H_][1]);                                  \
    ALOAD(stA[p_][H_][0], stA[p_][H_][1], x + aOff[H_] + tA_ * BK);            \
    gload_lds16(sbin + bOff[H_] + tB_ * BK, (char*)&ldsB[bWr_][0] + bDst[H_]); \
    if (H_) asm volatile("s_waitcnt vmcnt(6) lgkmcnt(0)" ::: "memory");        \
    half8 af0 = *(const half8*)((const char*)&ldsA[bRd_][0] + aRdB + ((H_)*4 + 0) * 1024); \
    half8 af1 = *(const half8*)((const char*)&ldsA[bRd_][0] + aRdB + ((H_)*4 + 1) * 1024); \
    half8 af2 = *(const half8*)((const char*)&ldsA[bRd_][0] + aRdB + ((H_)*4 + 2) * 1024); \
    half8 af3 = *(const half8*)((const char*)&ldsA[bRd_][0] + aRdB + ((H_)*4 + 3) * 1024); \
    if (!(H_)) {                                                               \
      bf0 = *(const half8*)((const char*)&ldsB[bRd_][0] + bRdB + 0);           \
      bf1 = *(const half8*)((const char*)&ldsB[bRd_][0] + bRdB + 1024);        \
      bf2 = *(const half8*)((const char*)&ldsB[bRd_][0] + bRdB + 2048);        \
      bf3 = *(const half8*)((const char*)&ldsB[bRd_][0] + bRdB + 3072);        \
    }                                                                          \
    __builtin_amdgcn_s_barrier();                                              \
    __builtin_amdgcn_s_setprio(1);                                             \
    acc[(H_)*4 + 0][0] = __builtin_amdgcn_mfma_f32_16x16x32_f16(af0, bf0, acc[(H_)*4 + 0][0], 0, 0, 0); \
    acc[(H_)*4 + 0][1] = __builtin_amdgcn_mfma_f32_16x16x32_f16(af0, bf1, acc[(H_)*4 + 0][1], 0, 0, 0); \
    acc[(H_)*4 + 0][2] = __builtin_amdgcn_mfma_f32_16x16x32_f16(af0, bf2, acc[(H_)*4 + 0][2], 0, 0, 0); \
    acc[(H_)*4 + 0][3] = __builtin_amdgcn_mfma_f32_16x16x32_f16(af0, bf3, acc[(H_)*4 + 0][3], 0, 0, 0); \
    acc[(H_)*4 + 1][0] = __builtin_amdgcn_mfma_f32_16x16x32_f16(af1, bf0, acc[(H_)*4 + 1][0], 0, 0, 0); \
    acc[(H_)*4 + 1][1] = __builtin_amdgcn_mfma_f32_16x16x32_f16(af1, bf1, acc[(H_)*4 + 1][1], 0, 0, 0); \
    acc[(H_)*4 + 1][2] = __builtin_amdgcn_mfma_f32_16x16x32_f16(af1, bf2, acc[(H_)*4 + 1][2], 0, 0, 0); \
    acc[(H_)*4 + 1][3] = __builtin_amdgcn_mfma_f32_16x16x32_f16(af1, bf3, acc[(H_)*4 + 1][3], 0, 0, 0); \
    acc[(H_)*4 + 2][0] = __builtin_amdgcn_mfma_f32_16x16x32_f16(af2, bf0, acc[(H_)*4 + 2][0], 0, 0, 0); \
    acc[(H_)*4 + 2][1] = __builtin_amdgcn_mfma_f32_16x16x32_f16(af2, bf1, acc[(H_)*4 + 2][1], 0, 0, 0); \
    acc[(H_)*4 + 2][2] = __builtin_amdgcn_mfma_f32_16x16x32_f16(af2, bf2, acc[(H_)*4 + 2][2], 0, 0, 0); \
    acc[(H_)*4 + 2][3] = __builtin_amdgcn_mfma_f32_16x16x32_f16(af2, bf3, acc[(H_)*4 + 2][3], 0, 0, 0); \
    acc[(H_)*4 + 3][0] = __builtin_amdgcn_mfma_f32_16x16x32_f16(af3, bf0, acc[(H_)*4 + 3][0], 0, 0, 0); \
    acc[(H_)*4 + 3][1] = __builtin_amdgcn_mfma_f32_16x16x32_f16(af3, bf1, acc[(H_)*4 + 3][1], 0, 0, 0); \
    acc[(H_)*4 + 3][2] = __builtin_amdgcn_mfma_f32_16x16x32_f16(af3, bf2, acc[(H_)*4 + 3][2], 0, 0, 0); \
    acc[(H_)*4 + 3][3] = __builtin_amdgcn_mfma_f32_16x16x32_f16(af3, bf3, acc[(H_)*4 + 3][3], 0, 0, 0); \
    __builtin_amdgcn_s_setprio(0);                                             \
    __builtin_amdgcn_s_barrier();                                              \
  }

#pragma unroll 1
  for (int tq = 0; tq < 8; ++tq) {
    const int TB = tq * 4;
    PH(TB + 0, 0, 0)
    PH(TB + 0, 0, 1)
    PH(TB + 1, 1, 0)
    PH(TB + 1, 1, 1)
    PH(TB + 2, 2, 0)
    PH(TB + 2, 2, 1)
    PH(TB + 3, 3, 0)
    PH(TB + 3, 3, 1)
  }
#undef PH

  // ---------------- epilogue: scale by alpha[col], store f32 ----------------
  float al[4];
#pragma unroll
  for (int n = 0; n < 4; ++n) al[n] = alpha[bn0 + wc * 64 + n * 16 + l15];
#pragma unroll
  for (int m = 0; m < 8; ++m) {
    const int row0 = bm0 + wr * 128 + m * 16 + kc * 4;
#pragma unroll
    for (int n = 0; n < 4; ++n) {
      const int col = bn0 + wc * 64 + n * 16 + l15;
#pragma unroll
      for (int j = 0; j < 4; ++j)
        out[(size_t)(row0 + j) * OUTF + col] = acc[m][n][j] * al[n];
    }
  }
}

extern "C" void kernel_launch(void* const* d_in, const int* in_sizes, int n_in,
                              void* d_out, int out_size, void* d_ws, size_t ws_size,
                              hipStream_t stream) {
  const float* x = (const float*)d_in[0];
  const float* w = (const float*)d_in[1];
  float* out = (float*)d_out;
  _Float16* sbin = (_Float16*)d_ws;                              // 2 MB
  float* alpha = (float*)((char*)d_ws + (size_t)OUTF * INF * 2); // 4 KB

  bl_prep<<<dim3(OUTF), dim3(256), 0, stream>>>(w, sbin, alpha);
  bl_gemm<<<dim3((TOKENS / BM) * (OUTF / BN)), dim3(512), 0, stream>>>(x, sbin, alpha, out);
}